// Round 1
// baseline (74.023 us; speedup 1.0000x reference)
//
#include <hip/hip_runtime.h>
#include <math.h>

// Problem constants (reference: N=1024, D=128, tau=1, beta=1)
#define NN 1024
#define DD 128

typedef __bf16 bf16x8 __attribute__((ext_vector_type(8)));
typedef float  floatx4 __attribute__((ext_vector_type(4)));

// Main kernel: grid (64, 2), block 256 (4 waves).
// Block (bx, p): rows i0 = bx*16 .. +15 of pair p (p=0: x vs label, p=1: x vs aug).
// Each wave owns a 16-wide j-tile per iteration; 16 iterations cover j=0..1023.
// d2_ij = nx_i + ny_j - 2 * dot(x_i, y_j); dot via bf16 MFMA, norms in exact fp32.
__global__ __launch_bounds__(256) void align_pair_kernel(
    const float* __restrict__ x,
    const float* __restrict__ y_center,
    const float* __restrict__ y_aug,
    float* __restrict__ partials /* [2*64] */)
{
    const float SCALE = 0.08838834764831845f;  // 1/sqrt(128)
    const int p    = blockIdx.y;
    const float* __restrict__ y = p ? y_aug : y_center;
    const int i0   = blockIdx.x * 16;
    const int tid  = threadIdx.x;
    const int w    = tid >> 6;    // wave 0..3
    const int lane = tid & 63;
    const int col  = lane & 15;   // fragment row (A) / col (C)
    const int quad = lane >> 4;   // 0..3

    // ---- A fragments: x rows i0+col, k = c*32 + quad*8 + [0..7] ----
    const float* xrow = x + (size_t)(i0 + col) * DD + quad * 8;
    bf16x8 afrag[4];
    float nx_own = 0.f;
#pragma unroll
    for (int c = 0; c < 4; ++c) {
        const float4 u0 = *(const float4*)(xrow + c * 32);
        const float4 u1 = *(const float4*)(xrow + c * 32 + 4);
        nx_own += u0.x*u0.x + u0.y*u0.y + u0.z*u0.z + u0.w*u0.w;
        nx_own += u1.x*u1.x + u1.y*u1.y + u1.z*u1.z + u1.w*u1.w;
        bf16x8 f;
        f[0]=(__bf16)u0.x; f[1]=(__bf16)u0.y; f[2]=(__bf16)u0.z; f[3]=(__bf16)u0.w;
        f[4]=(__bf16)u1.x; f[5]=(__bf16)u1.y; f[6]=(__bf16)u1.z; f[7]=(__bf16)u1.w;
        afrag[c] = f;
    }
    // full ||x_row||^2: sum the 4 quads (lanes differing in bits 4,5)
    nx_own += __shfl_xor(nx_own, 16);
    nx_own += __shfl_xor(nx_own, 32);
    // gather nx for this lane's 4 C-rows (row = quad*4 + r); lane r<16 holds nx of row r
    float nxr[4];
#pragma unroll
    for (int r = 0; r < 4; ++r) nxr[r] = __shfl(nx_own, quad * 4 + r);

    float denom[4] = {0.f, 0.f, 0.f, 0.f};  // per-lane partial (own col) row-sums of exp
    float pos[4]   = {0.f, 0.f, 0.f, 0.f};  // diagonal dm (at most one lane/tile hits)

    for (int t = 0; t < 16; ++t) {
        const int j0 = t * 64 + w * 16;
        const float* yrow = y + (size_t)(j0 + col) * DD + quad * 8;
        bf16x8 bfrag[4];
        float ny_own = 0.f;
#pragma unroll
        for (int c = 0; c < 4; ++c) {
            const float4 u0 = *(const float4*)(yrow + c * 32);
            const float4 u1 = *(const float4*)(yrow + c * 32 + 4);
            ny_own += u0.x*u0.x + u0.y*u0.y + u0.z*u0.z + u0.w*u0.w;
            ny_own += u1.x*u1.x + u1.y*u1.y + u1.z*u1.z + u1.w*u1.w;
            bf16x8 f;
            f[0]=(__bf16)u0.x; f[1]=(__bf16)u0.y; f[2]=(__bf16)u0.z; f[3]=(__bf16)u0.w;
            f[4]=(__bf16)u1.x; f[5]=(__bf16)u1.y; f[6]=(__bf16)u1.z; f[7]=(__bf16)u1.w;
            bfrag[c] = f;
        }
        ny_own += __shfl_xor(ny_own, 16);
        ny_own += __shfl_xor(ny_own, 32);   // ||y_(j0+col)||^2

        floatx4 acc = {0.f, 0.f, 0.f, 0.f};
#pragma unroll
        for (int c = 0; c < 4; ++c)
            acc = __builtin_amdgcn_mfma_f32_16x16x32_bf16(afrag[c], bfrag[c], acc, 0, 0, 0);

#pragma unroll
        for (int r = 0; r < 4; ++r) {
            const int row = quad * 4 + r;            // C row = quad*4 + reg
            float d2 = fmaf(-2.f, acc[r], nxr[r] + ny_own);
            d2 = fmaxf(d2, 0.f);
            const float dm = SCALE * sqrtf(d2);
            denom[r] += __expf(dm);
            if (j0 + col == i0 + row) pos[r] = dm;   // diagonal element
        }
    }

    // reduce across the 16 lanes (cols) of each quad group
#pragma unroll
    for (int r = 0; r < 4; ++r) {
#pragma unroll
        for (int m = 1; m < 16; m <<= 1) {
            denom[r] += __shfl_xor(denom[r], m);
            pos[r]   += __shfl_xor(pos[r], m);
        }
    }

    // cross-wave combine (each wave covered a disjoint j subset)
    __shared__ float ld_den[4][16];
    __shared__ float ld_pos[4][16];
    if (col == 0) {
#pragma unroll
        for (int r = 0; r < 4; ++r) {
            ld_den[w][quad * 4 + r] = denom[r];
            ld_pos[w][quad * 4 + r] = pos[r];
        }
    }
    __syncthreads();
    __shared__ float ld_c[16];
    if (tid < 16) {
        const float den = ld_den[0][tid] + ld_den[1][tid] + ld_den[2][tid] + ld_den[3][tid];
        const float po  = ld_pos[0][tid] + ld_pos[1][tid] + ld_pos[2][tid] + ld_pos[3][tid];
        ld_c[tid] = po - logf(den);   // contrib for row i0+tid
    }
    __syncthreads();
    if (tid == 0) {
        float s = 0.f;
#pragma unroll
        for (int k = 0; k < 16; ++k) s += ld_c[k];
        partials[p * 64 + blockIdx.x] = s;
    }
}

// Finalize: 1 block, 128 threads. partials[0..63] = center blocks, [64..127] = instance.
__global__ void align_finalize(const float* __restrict__ partials, float* __restrict__ out)
{
    const int tid = threadIdx.x;
    float v = partials[tid];
#pragma unroll
    for (int m = 1; m < 64; m <<= 1) v += __shfl_xor(v, m);
    __shared__ float s[2];
    if ((tid & 63) == 0) s[tid >> 6] = v;
    __syncthreads();
    if (tid == 0) {
        const float inv = 1.0f / (float)NN;
        const float c  = s[0] * inv;   // center alignment loss
        const float ia = s[1] * inv;   // instance alignment loss
        out[0] = c + ia;               // alignment_loss (beta = 1)
        out[1] = c;
        out[2] = ia;
    }
}

extern "C" void kernel_launch(void* const* d_in, const int* in_sizes, int n_in,
                              void* d_out, int out_size, void* d_ws, size_t ws_size,
                              hipStream_t stream) {
    // setup_inputs order: x, aug_x, label_prompt_embedding (all fp32 [1024,128])
    const float* x   = (const float*)d_in[0];
    const float* aug = (const float*)d_in[1];
    const float* lp  = (const float*)d_in[2];
    float* out       = (float*)d_out;
    float* partials  = (float*)d_ws;   // 128 floats

    align_pair_kernel<<<dim3(64, 2), 256, 0, stream>>>(x, lp, aug, partials);
    align_finalize<<<1, 128, 0, stream>>>(partials, out);
}

// Round 2
// 67.686 us; speedup vs baseline: 1.0936x; 1.0936x over previous
//
#include <hip/hip_runtime.h>
#include <math.h>

// Problem constants (reference: N=1024, D=128, tau=1, beta=1)
#define NN 1024
#define DD 128
#define JCH 8        // j-chunks per pair (each chunk = 128 columns)

typedef __bf16 bf16x8 __attribute__((ext_vector_type(8)));
typedef float  floatx4 __attribute__((ext_vector_type(4)));

// ws layout (bytes):
//   0        : bf16 matrices [3][1024][128]  (x, lp, aug)   = 786432
//   786432   : norms  [3][1024] f32                         = 12288
//   798720   : denom partials [2][JCH][1024] f32            = 65536
//   864256   : pos [2][1024] f32                            = 8192
#define WS_NORMS  786432
#define WS_DENOM  798720
#define WS_POS    864256

// ---------------- prep: fp32 -> bf16 + row norms ----------------
// grid 768 x 256: one wave per row, 3*1024 rows total.
__global__ __launch_bounds__(256) void align_prep(
    const float* __restrict__ x, const float* __restrict__ lp,
    const float* __restrict__ aug, __bf16* __restrict__ mats,
    float* __restrict__ norms)
{
    const int w    = threadIdx.x >> 6;
    const int lane = threadIdx.x & 63;
    const int gw   = blockIdx.x * 4 + w;          // 0..3071
    const int a    = gw >> 10;                    // array 0..2
    const int r    = gw & 1023;                   // row
    const float* src = (a == 0 ? x : (a == 1 ? lp : aug)) + (size_t)r * DD + lane * 2;
    const float2 v = *(const float2*)src;
    float sq = v.x * v.x + v.y * v.y;
    union { __bf16 b[2]; unsigned u; } t;
    t.b[0] = (__bf16)v.x; t.b[1] = (__bf16)v.y;
    *(unsigned*)(mats + (size_t)a * (NN * DD) + (size_t)r * DD + lane * 2) = t.u;
#pragma unroll
    for (int m = 1; m < 64; m <<= 1) sq += __shfl_xor(sq, m);
    if (lane == 0) norms[a * NN + r] = sq;
}

// ---------------- main: per (i-tile, pair, j-chunk) partial softmax-denoms ----
// grid (64, 2, JCH), block 256 (4 waves). Wave w covers j = jc*128 + t*64 + w*16,
// t = 0..1. d2_ij = nx_i + ny_j - 2*dot; dot via bf16 MFMA.
__global__ __launch_bounds__(256) void align_pair_kernel(
    const __bf16* __restrict__ mats, const float* __restrict__ norms,
    float* __restrict__ denom_part, float* __restrict__ posbuf)
{
    const float SCALE = 0.08838834764831845f;  // 1/sqrt(128)
    const int bx = blockIdx.x;     // i-tile (16 rows)
    const int p  = blockIdx.y;     // 0: x vs lp, 1: x vs aug
    const int jc = blockIdx.z;     // j-chunk (128 cols)
    const __bf16* __restrict__ A = mats;                              // x
    const __bf16* __restrict__ B = mats + (size_t)(p ? 2 : 1) * (NN * DD);
    const float*  __restrict__ nx = norms;
    const float*  __restrict__ ny = norms + (p ? 2 : 1) * NN;

    const int i0   = bx * 16;
    const int tid  = threadIdx.x;
    const int w    = tid >> 6;
    const int lane = tid & 63;
    const int col  = lane & 15;
    const int quad = lane >> 4;

    // A fragments: row i0+col, k = c*32 + quad*8 + [0..7]
    const __bf16* arow = A + (size_t)(i0 + col) * DD + quad * 8;
    bf16x8 afrag[4];
#pragma unroll
    for (int c = 0; c < 4; ++c) afrag[c] = *(const bf16x8*)(arow + c * 32);
    // norms for this lane's 4 C-rows (row = quad*4 + r)
    const float4 nxr = *(const float4*)(nx + i0 + quad * 4);

    float denom[4] = {0.f, 0.f, 0.f, 0.f};
    float pos[4]   = {0.f, 0.f, 0.f, 0.f};

#pragma unroll
    for (int t = 0; t < 2; ++t) {
        const int j0 = jc * 128 + t * 64 + w * 16;
        const __bf16* brow = B + (size_t)(j0 + col) * DD + quad * 8;
        bf16x8 bfrag[4];
#pragma unroll
        for (int c = 0; c < 4; ++c) bfrag[c] = *(const bf16x8*)(brow + c * 32);
        const float nyv = ny[j0 + col];   // norm of column j0+col

        floatx4 acc = {0.f, 0.f, 0.f, 0.f};
#pragma unroll
        for (int c = 0; c < 4; ++c)
            acc = __builtin_amdgcn_mfma_f32_16x16x32_bf16(afrag[c], bfrag[c], acc, 0, 0, 0);

#pragma unroll
        for (int r = 0; r < 4; ++r) {
            const int row = quad * 4 + r;          // C: col=lane&15, row=quad*4+r
            float d2 = fmaf(-2.f, acc[r], nxr[r] + nyv);
            d2 = fmaxf(d2, 0.f);
            const float dm = SCALE * sqrtf(d2);
            denom[r] += __expf(dm);
            if (j0 + col == i0 + row) pos[r] = dm;
        }
    }

    // reduce across the 16 cols of each quad group
#pragma unroll
    for (int r = 0; r < 4; ++r) {
#pragma unroll
        for (int m = 1; m < 16; m <<= 1) {
            denom[r] += __shfl_xor(denom[r], m);
            pos[r]   += __shfl_xor(pos[r], m);
        }
    }

    __shared__ float ld_den[4][16];
    __shared__ float ld_pos[4][16];
    if (col == 0) {
#pragma unroll
        for (int r = 0; r < 4; ++r) {
            ld_den[w][quad * 4 + r] = denom[r];
            ld_pos[w][quad * 4 + r] = pos[r];
        }
    }
    __syncthreads();
    if (tid < 16) {
        const float den = ld_den[0][tid] + ld_den[1][tid] + ld_den[2][tid] + ld_den[3][tid];
        denom_part[(size_t)(p * JCH + jc) * NN + i0 + tid] = den;
        if (jc == (bx >> 3)) {   // this chunk contains the diagonal for rows i0..i0+15
            const float po = ld_pos[0][tid] + ld_pos[1][tid] + ld_pos[2][tid] + ld_pos[3][tid];
            posbuf[p * NN + i0 + tid] = po;
        }
    }
}

// ---------------- finalize: 1 block, 1024 threads (thread = row) -------------
__global__ __launch_bounds__(1024) void align_finalize(
    const float* __restrict__ denom_part, const float* __restrict__ posbuf,
    float* __restrict__ out)
{
    const int tid  = threadIdx.x;   // row 0..1023
    const int w    = tid >> 6;
    const int lane = tid & 63;
    float contrib[2];
#pragma unroll
    for (int p = 0; p < 2; ++p) {
        float den = 0.f;
#pragma unroll
        for (int jc = 0; jc < JCH; ++jc)
            den += denom_part[(size_t)(p * JCH + jc) * NN + tid];
        contrib[p] = posbuf[p * NN + tid] - __logf(den);
    }
    float c0 = contrib[0], c1 = contrib[1];
#pragma unroll
    for (int m = 1; m < 64; m <<= 1) {
        c0 += __shfl_xor(c0, m);
        c1 += __shfl_xor(c1, m);
    }
    __shared__ float s0[16], s1[16];
    if (lane == 0) { s0[w] = c0; s1[w] = c1; }
    __syncthreads();
    if (tid == 0) {
        float a = 0.f, b = 0.f;
#pragma unroll
        for (int k = 0; k < 16; ++k) { a += s0[k]; b += s1[k]; }
        const float inv = 1.0f / (float)NN;
        const float c  = a * inv;   // center alignment loss
        const float ia = b * inv;   // instance alignment loss
        out[0] = c + ia;
        out[1] = c;
        out[2] = ia;
    }
}

extern "C" void kernel_launch(void* const* d_in, const int* in_sizes, int n_in,
                              void* d_out, int out_size, void* d_ws, size_t ws_size,
                              hipStream_t stream) {
    const float* x   = (const float*)d_in[0];
    const float* aug = (const float*)d_in[1];
    const float* lp  = (const float*)d_in[2];
    float* out       = (float*)d_out;

    char* ws = (char*)d_ws;
    __bf16* mats      = (__bf16*)ws;
    float*  norms     = (float*)(ws + WS_NORMS);
    float*  denom_par = (float*)(ws + WS_DENOM);
    float*  posbuf    = (float*)(ws + WS_POS);

    align_prep<<<768, 256, 0, stream>>>(x, lp, aug, mats, norms);
    align_pair_kernel<<<dim3(64, 2, JCH), 256, 0, stream>>>(mats, norms, denom_par, posbuf);
    align_finalize<<<1, 1024, 0, stream>>>(denom_par, posbuf, out);
}